// Round 3
// baseline (613.140 us; speedup 1.0000x reference)
//
#include <hip/hip_runtime.h>
#include <cstdint>
#include <cstddef>

typedef __bf16 bf16_t;
typedef __bf16 bf16x8 __attribute__((ext_vector_type(8)));
typedef __bf16 bf16x4 __attribute__((ext_vector_type(4)));
typedef float  f32x4  __attribute__((ext_vector_type(4)));

#define MFMA(a, b, c) __builtin_amdgcn_mfma_f32_16x16x32_bf16((a), (b), (c), 0, 0, 0)

// BS=64, S=128, DM=512, H=8, DK=DV=512, PRED=96, NF=65536

// ---------------------------------------------------------------- converts
__global__ __launch_bounds__(256) void k_convert(const float* __restrict__ in,
                                                 bf16_t* __restrict__ out, int n) {
  int i = (blockIdx.x * 256 + threadIdx.x) * 4;
  if (i < n) {
    float4 v = *(const float4*)(in + i);
    bf16x4 o;
    o[0] = (bf16_t)v.x; o[1] = (bf16_t)v.y; o[2] = (bf16_t)v.z; o[3] = (bf16_t)v.w;
    *(bf16x4*)(out + i) = o;
  }
}

// out[c][r] = (bf16) in[r][c]   (R,C multiples of 32)
__global__ __launch_bounds__(256) void k_transpose_convert(const float* __restrict__ in,
                                                           bf16_t* __restrict__ out,
                                                           int R, int C) {
  __shared__ float tile[32][33];
  int tx = threadIdx.x & 31, ty = threadIdx.x >> 5;
  int c0 = blockIdx.x * 32, r0 = blockIdx.y * 32;
#pragma unroll
  for (int j = 0; j < 4; ++j)
    tile[ty + j * 8][tx] = in[(size_t)(r0 + ty + j * 8) * C + c0 + tx];
  __syncthreads();
#pragma unroll
  for (int j = 0; j < 4; ++j)
    out[(size_t)(c0 + ty + j * 8) * R + r0 + tx] = (bf16_t)tile[tx][ty + j * 8];
}

// batched bf16 transpose: in [b][R][C] -> out [b][C][R], grid (C/32, R/32, B)
__global__ __launch_bounds__(256) void k_transpose_b16(const bf16_t* __restrict__ in,
                                                       bf16_t* __restrict__ out,
                                                       int R, int C) {
  __shared__ bf16_t tile[32][34];
  size_t base = (size_t)blockIdx.z * R * C;
  int tx = threadIdx.x & 31, ty = threadIdx.x >> 5;
  int c0 = blockIdx.x * 32, r0 = blockIdx.y * 32;
#pragma unroll
  for (int j = 0; j < 4; ++j)
    tile[ty + j * 8][tx] = in[base + (size_t)(r0 + ty + j * 8) * C + c0 + tx];
  __syncthreads();
#pragma unroll
  for (int j = 0; j < 4; ++j)
    out[base + (size_t)(c0 + ty + j * 8) * R + r0 + tx] = tile[tx][ty + j * 8];
}

// ---------------------------------------------------------------- weight products
// out[(h*512+n)*512+m] = sum_k A[m][h*512+k] * B(n,k)   (f32 out, transposed store)
// BMODE 0: B(n,k) = Bp[n*ldB + h*512 + k]   (Wqk: A=Wq, B=Wk, ldB=4096)
// BMODE 1: B(n,k) = Bp[(h*512+k)*ldB + n]   (Wvo: A=Wv, B=Wo, ldB=512)
template <int BMODE>
__global__ __launch_bounds__(256) void k_wprod(const float* __restrict__ Ap,
                                               const float* __restrict__ Bp,
                                               float* __restrict__ out,
                                               int ldA, int ldB) {
  __shared__ __align__(16) bf16_t As[128 * 68];
  __shared__ __align__(16) bf16_t Bs[128 * 68];
  const int tid = threadIdx.x, lane = tid & 63, wave = tid >> 6;
  const int wr = (wave >> 1) * 64, wc = (wave & 1) * 64;
  const int lr = lane & 15, lk = (lane >> 4) * 8, frow = (lane >> 4) * 4;
  const int m0 = blockIdx.x * 128, n0 = blockIdx.y * 128, h = blockIdx.z;
  const int sr = tid >> 3, sc = (tid & 7) * 8;
  f32x4 acc[4][4] = {};

  for (int kt = 0; kt < 512; kt += 64) {
#pragma unroll
    for (int rr = 0; rr < 4; ++rr) {
      int r = sr + 32 * rr;
      const float* ap = Ap + (size_t)(m0 + r) * ldA + h * 512 + kt + sc;
      bf16x8 av;
#pragma unroll
      for (int e = 0; e < 8; ++e) av[e] = (bf16_t)ap[e];
      *(bf16x8*)(As + r * 68 + sc) = av;
    }
    if (BMODE == 0) {
#pragma unroll
      for (int rr = 0; rr < 4; ++rr) {
        int r = sr + 32 * rr;
        const float* bp = Bp + (size_t)(n0 + r) * ldB + h * 512 + kt + sc;
        bf16x8 bv;
#pragma unroll
        for (int e = 0; e < 8; ++e) bv[e] = (bf16_t)bp[e];
        *(bf16x8*)(Bs + r * 68 + sc) = bv;
      }
    } else {
      // rows k (64), cols n (128): thread reads float4 along n, scatters transposed
#pragma unroll
      for (int rr = 0; rr < 8; ++rr) {
        int kr = (tid >> 5) + 8 * rr;          // 0..63
        int nc = (tid & 31) * 4;               // 0..124
        const float* bp = Bp + (size_t)(h * 512 + kt + kr) * ldB + n0 + nc;
        float4 v = *(const float4*)bp;
        Bs[(nc + 0) * 68 + kr] = (bf16_t)v.x;
        Bs[(nc + 1) * 68 + kr] = (bf16_t)v.y;
        Bs[(nc + 2) * 68 + kr] = (bf16_t)v.z;
        Bs[(nc + 3) * 68 + kr] = (bf16_t)v.w;
      }
    }
    __syncthreads();
#pragma unroll
    for (int kk = 0; kk < 2; ++kk) {
      bf16x8 af[4], bfr[4];
#pragma unroll
      for (int i = 0; i < 4; ++i)
        af[i] = *(const bf16x8*)(As + (wr + i * 16 + lr) * 68 + kk * 32 + lk);
#pragma unroll
      for (int j = 0; j < 4; ++j)
        bfr[j] = *(const bf16x8*)(Bs + (wc + j * 16 + lr) * 68 + kk * 32 + lk);
#pragma unroll
      for (int i = 0; i < 4; ++i)
#pragma unroll
        for (int j = 0; j < 4; ++j)
          acc[i][j] = MFMA(af[i], bfr[j], acc[i][j]);
    }
    __syncthreads();
  }
#pragma unroll
  for (int i = 0; i < 4; ++i)
#pragma unroll
    for (int j = 0; j < 4; ++j)
#pragma unroll
      for (int q = 0; q < 4; ++q) {
        int gm = m0 + wr + i * 16 + frow + q;
        int gn = n0 + wc + j * 16 + lr;
        out[(size_t)(h * 512 + gn) * 512 + gm] = acc[i][j][q];
      }
}

// ---------------------------------------------------------------- bias helpers
// W1[i][h] = sum_d Wq[i][h*512+d]*bk[h*512+d]; W2 same with (Wk,bq); c[h]=bq.bk
__global__ __launch_bounds__(256) void k_sbias(const float* __restrict__ Wq,
                                               const float* __restrict__ bk,
                                               const float* __restrict__ Wk,
                                               const float* __restrict__ bq,
                                               float* __restrict__ W1,
                                               float* __restrict__ W2,
                                               float* __restrict__ c) {
  const int lane = threadIdx.x & 63, wave = threadIdx.x >> 6;
  const int i = blockIdx.x * 4 + wave;  // [0,512)
  for (int h = 0; h < 8; ++h) {
    float s1 = 0.f, s2 = 0.f;
    for (int d = lane; d < 512; d += 64) {
      s1 += Wq[(size_t)i * 4096 + h * 512 + d] * bk[h * 512 + d];
      s2 += Wk[(size_t)i * 4096 + h * 512 + d] * bq[h * 512 + d];
    }
#pragma unroll
    for (int o = 32; o > 0; o >>= 1) { s1 += __shfl_down(s1, o); s2 += __shfl_down(s2, o); }
    if (lane == 0) { W1[i * 8 + h] = s1; W2[i * 8 + h] = s2; }
  }
  if (blockIdx.x == 0 && wave == 0) {
    for (int h = 0; h < 8; ++h) {
      float cc = 0.f;
      for (int d = lane; d < 512; d += 64) cc += bq[h * 512 + d] * bk[h * 512 + d];
#pragma unroll
      for (int o = 32; o > 0; o >>= 1) cc += __shfl_down(cc, o);
      if (lane == 0) c[h] = cc;
    }
  }
}

// cvec[d] = sum_n bv[n]*Wo[n][d] + bo[d]
__global__ __launch_bounds__(256) void k_cvec(const float* __restrict__ bv,
                                              const float* __restrict__ Wo,
                                              const float* __restrict__ bo,
                                              float* __restrict__ cvec) {
  int d = blockIdx.x * 256 + threadIdx.x;
  float s = 0.f;
  for (int n = 0; n < 4096; ++n) s += bv[n] * Wo[(size_t)n * 512 + d];
  cvec[d] = s + bo[d];
}

__global__ __launch_bounds__(256) void k_zero(float* __restrict__ p, int n4) {
  int i = blockIdx.x * 256 + threadIdx.x;
  if (i < n4) *(float4*)(p + i * 4) = float4{0.f, 0.f, 0.f, 0.f};
}

// o1b = bf16(o1acc + cvec[col])
__global__ __launch_bounds__(256) void k_final(const float* __restrict__ o1acc,
                                               const float* __restrict__ cvec,
                                               bf16_t* __restrict__ o1b, int n4) {
  int i = blockIdx.x * 256 + threadIdx.x;
  if (i < n4) {
    float4 v = *(const float4*)(o1acc + i * 4);
    float4 cv = *(const float4*)(cvec + ((i * 4) & 511));
    bf16x4 o;
    o[0] = (bf16_t)(v.x + cv.x); o[1] = (bf16_t)(v.y + cv.y);
    o[2] = (bf16_t)(v.z + cv.z); o[3] = (bf16_t)(v.w + cv.w);
    *(bf16x4*)(o1b + i * 4) = o;
  }
}

// ---------------------------------------------------------------- fused attention
// grid 512: bx = b*8+h. Computes, per (b,h):
//   T = x_b @ Wqk_h (chunked 64 cols), S = T @ x_b^T (+bias rank-1 +prev, *scale),
//   P = softmax(S), xvo = x_b @ Wvo_h (chunked), o1acc += P @ xvo  (f32 atomics)
__global__ __launch_bounds__(256, 2) void k_fattn(const bf16_t* __restrict__ xb,
                                                  const float* __restrict__ wqkB,
                                                  const float* __restrict__ wvoB,
                                                  const float* __restrict__ prev,
                                                  const float* __restrict__ scale_p,
                                                  const float* __restrict__ W1,
                                                  const float* __restrict__ W2,
                                                  const float* __restrict__ cb,
                                                  float* __restrict__ o1acc) {
  __shared__ __align__(16) bf16_t Xs[128 * 68];   // 17408 B
  __shared__ __align__(16) bf16_t Ws[64 * 68];    //  8704 B
  __shared__ __align__(16) bf16_t Tl[128 * 68];   // 17408 B (phase2: [64][132])
  __shared__ __align__(16) bf16_t Pl[128 * 132];  // 33792 B
  __shared__ float T1s[128], T2s[128];
  __shared__ float csh;

  const int tid = threadIdx.x, lane = tid & 63, wave = tid >> 6;
  const int lr = lane & 15, lk = (lane >> 4) * 8, frow = (lane >> 4) * 4;
  const int wrow = wave * 32;
  const int sr = tid >> 3, sc = (tid & 7) * 8;
  const int b = blockIdx.x >> 3, h = blockIdx.x & 7;
  const bf16_t* xB = xb + (size_t)b * 128 * 512;

  // ---- prologue: bias vectors T1s,T2s and scalar c
  {
    int q = tid & 127, part = tid >> 7;
    float s1 = 0.f, s2 = 0.f;
    const bf16_t* xrow = xB + (size_t)q * 512;
    for (int i = part * 256; i < part * 256 + 256; ++i) {
      float xv = (float)xrow[i];
      s1 += xv * W1[i * 8 + h];
      s2 += xv * W2[i * 8 + h];
    }
    float* scr = (float*)Pl;
    scr[tid] = s1; scr[256 + tid] = s2;
    if (tid == 0) csh = cb[h];
    __syncthreads();
    if (tid < 128) {
      T1s[tid] = scr[tid] + scr[tid + 128];
      T2s[tid] = scr[tid + 256] + scr[tid + 384];
    }
    __syncthreads();
  }

  // ---- phase 1: S = (x Wqk) x^T, chunked over i' (8 x 64)
  f32x4 sacc[2][8] = {};
  for (int ic = 0; ic < 8; ++ic) {
    f32x4 tacc[2][4] = {};
    for (int kt = 0; kt < 8; ++kt) {
#pragma unroll
      for (int rr = 0; rr < 4; ++rr) {
        int r = sr + 32 * rr;
        *(bf16x8*)(Xs + r * 68 + sc) = *(const bf16x8*)(xB + (size_t)r * 512 + kt * 64 + sc);
      }
#pragma unroll
      for (int rr = 0; rr < 2; ++rr) {
        int n = sr + 32 * rr;
        const float* wp = wqkB + (size_t)(h * 512 + ic * 64 + n) * 512 + kt * 64 + sc;
        bf16x8 wv;
#pragma unroll
        for (int e = 0; e < 8; ++e) wv[e] = (bf16_t)wp[e];
        *(bf16x8*)(Ws + n * 68 + sc) = wv;
      }
      __syncthreads();
#pragma unroll
      for (int kk = 0; kk < 2; ++kk) {
        bf16x8 af[2], bfr[4];
#pragma unroll
        for (int i = 0; i < 2; ++i)
          af[i] = *(const bf16x8*)(Xs + (wrow + i * 16 + lr) * 68 + kk * 32 + lk);
#pragma unroll
        for (int j = 0; j < 4; ++j)
          bfr[j] = *(const bf16x8*)(Ws + (j * 16 + lr) * 68 + kk * 32 + lk);
#pragma unroll
        for (int i = 0; i < 2; ++i)
#pragma unroll
          for (int j = 0; j < 4; ++j)
            tacc[i][j] = MFMA(af[i], bfr[j], tacc[i][j]);
      }
      __syncthreads();
    }
    // restage Xs with i'-chunk cols; write T to Tl
#pragma unroll
    for (int rr = 0; rr < 4; ++rr) {
      int r = sr + 32 * rr;
      *(bf16x8*)(Xs + r * 68 + sc) = *(const bf16x8*)(xB + (size_t)r * 512 + ic * 64 + sc);
    }
#pragma unroll
    for (int i2 = 0; i2 < 2; ++i2)
#pragma unroll
      for (int j2 = 0; j2 < 4; ++j2)
#pragma unroll
        for (int e = 0; e < 4; ++e)
          Tl[(wrow + i2 * 16 + frow + e) * 68 + j2 * 16 + lr] = (bf16_t)tacc[i2][j2][e];
    __syncthreads();
#pragma unroll
    for (int kk = 0; kk < 2; ++kk) {
      bf16x8 af[2], bfr[8];
#pragma unroll
      for (int i = 0; i < 2; ++i)
        af[i] = *(const bf16x8*)(Tl + (wrow + i * 16 + lr) * 68 + kk * 32 + lk);
#pragma unroll
      for (int j = 0; j < 8; ++j)
        bfr[j] = *(const bf16x8*)(Xs + (j * 16 + lr) * 68 + kk * 32 + lk);
#pragma unroll
      for (int i = 0; i < 2; ++i)
#pragma unroll
        for (int j = 0; j < 8; ++j)
          sacc[i][j] = MFMA(af[i], bfr[j], sacc[i][j]);
    }
    __syncthreads();
  }

  // ---- softmax (rows live in 16-lane groups)
  const float scl = scale_p[0];
#pragma unroll
  for (int i2 = 0; i2 < 2; ++i2) {
#pragma unroll
    for (int e = 0; e < 4; ++e) {
      const int row = wrow + i2 * 16 + frow + e;
      const float* prow = prev + ((size_t)(b * 8 + h) * 128 + row) * 128;
      float mx = -3.4e38f;
#pragma unroll
      for (int j = 0; j < 8; ++j) {
        int col = j * 16 + lr;
        float v = scl * (sacc[i2][j][e] + T1s[row] + T2s[col] + csh) + prow[col];
        sacc[i2][j][e] = v;
        mx = fmaxf(mx, v);
      }
      mx = fmaxf(mx, __shfl_xor(mx, 1));
      mx = fmaxf(mx, __shfl_xor(mx, 2));
      mx = fmaxf(mx, __shfl_xor(mx, 4));
      mx = fmaxf(mx, __shfl_xor(mx, 8));
      float sum = 0.f;
#pragma unroll
      for (int j = 0; j < 8; ++j) {
        float p = __expf(sacc[i2][j][e] - mx);
        sacc[i2][j][e] = p;
        sum += p;
      }
      sum += __shfl_xor(sum, 1);
      sum += __shfl_xor(sum, 2);
      sum += __shfl_xor(sum, 4);
      sum += __shfl_xor(sum, 8);
      float inv = 1.f / sum;
#pragma unroll
      for (int j = 0; j < 8; ++j)
        Pl[row * 132 + j * 16 + lr] = (bf16_t)(sacc[i2][j][e] * inv);
    }
  }
  __syncthreads();

  // ---- phase 2: o1 += P @ (x Wvo), chunked over d' (8 x 64)
  for (int dc = 0; dc < 8; ++dc) {
    f32x4 vacc[2][4] = {};
    for (int kt = 0; kt < 8; ++kt) {
#pragma unroll
      for (int rr = 0; rr < 4; ++rr) {
        int r = sr + 32 * rr;
        *(bf16x8*)(Xs + r * 68 + sc) = *(const bf16x8*)(xB + (size_t)r * 512 + kt * 64 + sc);
      }
#pragma unroll
      for (int rr = 0; rr < 2; ++rr) {
        int n = sr + 32 * rr;
        const float* wp = wvoB + (size_t)(h * 512 + dc * 64 + n) * 512 + kt * 64 + sc;
        bf16x8 wv;
#pragma unroll
        for (int e = 0; e < 8; ++e) wv[e] = (bf16_t)wp[e];
        *(bf16x8*)(Ws + n * 68 + sc) = wv;
      }
      __syncthreads();
#pragma unroll
      for (int kk = 0; kk < 2; ++kk) {
        bf16x8 af[2], bfr[4];
#pragma unroll
        for (int i = 0; i < 2; ++i)
          af[i] = *(const bf16x8*)(Xs + (wrow + i * 16 + lr) * 68 + kk * 32 + lk);
#pragma unroll
        for (int j = 0; j < 4; ++j)
          bfr[j] = *(const bf16x8*)(Ws + (j * 16 + lr) * 68 + kk * 32 + lk);
#pragma unroll
        for (int i = 0; i < 2; ++i)
#pragma unroll
          for (int j = 0; j < 4; ++j)
            vacc[i][j] = MFMA(af[i], bfr[j], vacc[i][j]);
      }
      __syncthreads();
    }
    // write xvo transposed: Tl2[d'][s]  (stride 132)
#pragma unroll
    for (int i2 = 0; i2 < 2; ++i2)
#pragma unroll
      for (int j2 = 0; j2 < 4; ++j2)
#pragma unroll
        for (int e = 0; e < 4; ++e)
          Tl[(j2 * 16 + lr) * 132 + (wrow + i2 * 16 + frow + e)] = (bf16_t)vacc[i2][j2][e];
    __syncthreads();
    f32x4 oacc[2][4] = {};
#pragma unroll
    for (int kk = 0; kk < 4; ++kk) {
      bf16x8 af[2], bfr[4];
#pragma unroll
      for (int i = 0; i < 2; ++i)
        af[i] = *(const bf16x8*)(Pl + (wrow + i * 16 + lr) * 132 + kk * 32 + lk);
#pragma unroll
      for (int j = 0; j < 4; ++j)
        bfr[j] = *(const bf16x8*)(Tl + (j * 16 + lr) * 132 + kk * 32 + lk);
#pragma unroll
      for (int i = 0; i < 2; ++i)
#pragma unroll
        for (int j = 0; j < 4; ++j)
          oacc[i][j] = MFMA(af[i], bfr[j], oacc[i][j]);
    }
    __syncthreads();
#pragma unroll
    for (int i2 = 0; i2 < 2; ++i2)
#pragma unroll
      for (int j2 = 0; j2 < 4; ++j2)
#pragma unroll
        for (int e = 0; e < 4; ++e) {
          int row = b * 128 + wrow + i2 * 16 + frow + e;
          int col = dc * 64 + j2 * 16 + lr;
          atomicAdd(o1acc + (size_t)row * 512 + col, oacc[i2][j2][e]);
        }
  }
}

// ---------------------------------------------------------------- generic GEMM (tail)
// C[M][N] = A[M][K] @ Bt[N][K]^T + bias, optional relu. Row-major out.
template <int RELU>
__global__ __launch_bounds__(256) void k_gemm(const bf16_t* __restrict__ A,
                                              const bf16_t* __restrict__ Bt,
                                              const float* __restrict__ bias,
                                              bf16_t* __restrict__ C,
                                              int M, int N, int K) {
  __shared__ __align__(16) bf16_t As[128 * 68];
  __shared__ __align__(16) bf16_t Bs[128 * 68];
  const int tid = threadIdx.x, lane = tid & 63, wave = tid >> 6;
  const int wr = (wave >> 1) * 64, wc = (wave & 1) * 64;
  const int m0 = blockIdx.x * 128, n0 = blockIdx.y * 128;
  const int lr = lane & 15, lk = (lane >> 4) * 8, frow = (lane >> 4) * 4;
  const int sr = tid >> 3, sc = (tid & 7) * 8;
  f32x4 acc[4][4] = {};

  for (int kt = 0; kt < K; kt += 64) {
#pragma unroll
    for (int i = 0; i < 4; ++i) {
      int r = i * 32 + sr;
      *(bf16x8*)(As + r * 68 + sc) = *(const bf16x8*)(A + (size_t)(m0 + r) * K + kt + sc);
      *(bf16x8*)(Bs + r * 68 + sc) = *(const bf16x8*)(Bt + (size_t)(n0 + r) * K + kt + sc);
    }
    __syncthreads();
#pragma unroll
    for (int kk = 0; kk < 2; ++kk) {
      bf16x8 af[4], bfr[4];
#pragma unroll
      for (int i = 0; i < 4; ++i)
        af[i] = *(const bf16x8*)(As + (wr + i * 16 + lr) * 68 + kk * 32 + lk);
#pragma unroll
      for (int j = 0; j < 4; ++j)
        bfr[j] = *(const bf16x8*)(Bs + (wc + j * 16 + lr) * 68 + kk * 32 + lk);
#pragma unroll
      for (int i = 0; i < 4; ++i)
#pragma unroll
        for (int j = 0; j < 4; ++j)
          acc[i][j] = MFMA(af[i], bfr[j], acc[i][j]);
    }
    __syncthreads();
  }
#pragma unroll
  for (int j = 0; j < 4; ++j) {
    int gn = n0 + wc + j * 16 + lr;
    float bv = bias ? bias[gn] : 0.0f;
#pragma unroll
    for (int i = 0; i < 4; ++i) {
#pragma unroll
      for (int q = 0; q < 4; ++q) {
        int gm = m0 + wr + i * 16 + frow + q;
        float v = acc[i][j][q] + bv;
        if (RELU) v = v > 0.0f ? v : 0.0f;
        C[(size_t)gm * N + gn] = (bf16_t)v;
      }
    }
  }
}

// ---------------------------------------------------------------- head (split-K)
__global__ __launch_bounds__(256) void k_head_partial(const bf16_t* __restrict__ Z,
                                                      const bf16_t* __restrict__ WhT,
                                                      float* __restrict__ part) {
  __shared__ __align__(16) bf16_t As[64 * 68];
  __shared__ __align__(16) bf16_t Bs[96 * 68];
  const int tid = threadIdx.x, lane = tid & 63, wave = tid >> 6;
  const int wr = (wave >> 1) * 32, wc = (wave & 1) * 48;
  const int lr = lane & 15, lk = (lane >> 4) * 8, frow = (lane >> 4) * 4;
  const int k0 = blockIdx.x * 512;
  const int sr = tid >> 3, sc = (tid & 7) * 8;
  f32x4 acc[2][3] = {};
  for (int kt = 0; kt < 512; kt += 64) {
#pragma unroll
    for (int i = 0; i < 2; ++i) {
      int r = i * 32 + sr;
      *(bf16x8*)(As + r * 68 + sc) = *(const bf16x8*)(Z + (size_t)r * 65536 + k0 + kt + sc);
    }
#pragma unroll
    for (int i = 0; i < 3; ++i) {
      int r = i * 32 + sr;
      *(bf16x8*)(Bs + r * 68 + sc) = *(const bf16x8*)(WhT + (size_t)r * 65536 + k0 + kt + sc);
    }
    __syncthreads();
#pragma unroll
    for (int kk = 0; kk < 2; ++kk) {
      bf16x8 af[2], bfr[3];
#pragma unroll
      for (int i = 0; i < 2; ++i)
        af[i] = *(const bf16x8*)(As + (wr + i * 16 + lr) * 68 + kk * 32 + lk);
#pragma unroll
      for (int j = 0; j < 3; ++j)
        bfr[j] = *(const bf16x8*)(Bs + (wc + j * 16 + lr) * 68 + kk * 32 + lk);
#pragma unroll
      for (int i = 0; i < 2; ++i)
#pragma unroll
        for (int j = 0; j < 3; ++j)
          acc[i][j] = MFMA(af[i], bfr[j], acc[i][j]);
    }
    __syncthreads();
  }
#pragma unroll
  for (int i = 0; i < 2; ++i)
#pragma unroll
    for (int j = 0; j < 3; ++j)
#pragma unroll
      for (int q = 0; q < 4; ++q) {
        int m = wr + i * 16 + frow + q;
        int n = wc + j * 16 + lr;
        part[(size_t)blockIdx.x * 6144 + m * 96 + n] = acc[i][j][q];
      }
}

__global__ __launch_bounds__(256) void k_head_reduce(const float* __restrict__ part,
                                                     const float* __restrict__ bias,
                                                     float* __restrict__ out) {
  int idx = blockIdx.x * 256 + threadIdx.x;
  if (idx >= 6144) return;
  float s = bias[idx % 96];
  for (int kb = 0; kb < 128; ++kb) s += part[(size_t)kb * 6144 + idx];
  out[idx] = s;
}

__global__ void k_sentinel(float* out, int n, float val) {
  int i = blockIdx.x * 256 + threadIdx.x;
  if (i < n) out[i] = val;
}

// ---------------------------------------------------------------- launch
extern "C" void kernel_launch(void* const* d_in, const int* in_sizes, int n_in,
                              void* d_out, int out_size, void* d_ws, size_t ws_size,
                              hipStream_t stream) {
  const float* x    = (const float*)d_in[0];
  const float* prev = (const float*)d_in[1];
  const float* Wq = (const float*)d_in[2];   const float* bq = (const float*)d_in[3];
  const float* Wk = (const float*)d_in[4];   const float* bk = (const float*)d_in[5];
  const float* Wv = (const float*)d_in[6];   const float* bv = (const float*)d_in[7];
  const float* Wo = (const float*)d_in[8];   const float* bo = (const float*)d_in[9];
  const float* scale = (const float*)d_in[10];
  const float* Wi1 = (const float*)d_in[11]; const float* bi1 = (const float*)d_in[12];
  const float* Wi2 = (const float*)d_in[13]; const float* bi2 = (const float*)d_in[14];
  const float* Wt1 = (const float*)d_in[15]; const float* bt1 = (const float*)d_in[16];
  const float* Wt2 = (const float*)d_in[17]; const float* bt2 = (const float*)d_in[18];
  const float* Wh = (const float*)d_in[19];  const float* bh = (const float*)d_in[20];
  float* out = (float*)d_out;

  char* p = (char*)d_ws;
  auto carve = [&](size_t bytes) {
    char* r = p;
    p += (bytes + 255) & ~(size_t)255;
    return r;
  };
  bf16_t* xb    = (bf16_t*)carve((size_t)8192 * 512 * 2);   // 8.39 MB
  bf16_t* o1b   = (bf16_t*)carve((size_t)8192 * 512 * 2);   // 8.39 MB
  float*  W1    = (float*)carve(512 * 8 * 4);
  float*  W2    = (float*)carve(512 * 8 * 4);
  float*  cb    = (float*)carve(8 * 4);
  float*  cvec  = (float*)carve(512 * 4);
  float*  o1acc = (float*)carve((size_t)8192 * 512 * 4);    // 16.78 MB
  char*   arena = carve((size_t)2 * 4096 * 512 * 4);        // 33.55 MB
  // attention-phase view of arena:
  float* wqkB = (float*)arena;
  float* wvoB = (float*)(arena + (size_t)4096 * 512 * 4);
  // tail view of arena (used only AFTER k_fattn):
  char* q2 = arena;
  auto carve2 = [&](size_t bytes) {
    char* r = q2;
    q2 += (bytes + 255) & ~(size_t)255;
    return r;
  };
  bf16_t* whT  = (bf16_t*)carve2((size_t)96 * 65536 * 2);   // 12.58 MB
  bf16_t* wt1T = (bf16_t*)carve2((size_t)512 * 512 * 2);
  bf16_t* wt2T = (bf16_t*)carve2((size_t)512 * 512 * 2);
  bf16_t* wi1T = (bf16_t*)carve2((size_t)128 * 128 * 2);
  bf16_t* wi2T = (bf16_t*)carve2((size_t)128 * 128 * 2);
  float*  hp   = (float*)carve2((size_t)128 * 64 * 96 * 4); // 3.15 MB
  bf16_t* bufB = (bf16_t*)carve2((size_t)8192 * 512 * 2);   // 8.39 MB

  if ((size_t)(p - (char*)d_ws) > ws_size) {
    k_sentinel<<<24, 256, 0, stream>>>(out, 6144, (float)ws_size);
    return;
  }

  dim3 blk(256);
  // ---- prep
  k_convert<<<4096, blk, 0, stream>>>(x, xb, 8192 * 512);
  k_wprod<0><<<dim3(4, 4, 8), blk, 0, stream>>>(Wq, Wk, wqkB, 4096, 4096);
  k_wprod<1><<<dim3(4, 4, 8), blk, 0, stream>>>(Wv, Wo, wvoB, 4096, 512);
  k_sbias<<<128, blk, 0, stream>>>(Wq, bk, Wk, bq, W1, W2, cb);
  k_cvec<<<2, blk, 0, stream>>>(bv, Wo, bo, cvec);
  k_zero<<<4096, blk, 0, stream>>>(o1acc, 1048576);

  // ---- fused attention (+Wo fold) -> o1acc
  k_fattn<<<512, blk, 0, stream>>>(xb, wqkB, wvoB, prev, scale, W1, W2, cb, o1acc);
  k_final<<<4096, blk, 0, stream>>>(o1acc, cvec, o1b, 1048576);

  // ---- tail weight converts (arena now safe to overwrite)
  k_transpose_convert<<<dim3(4, 4), blk, 0, stream>>>(Wi1, wi1T, 128, 128);
  k_transpose_convert<<<dim3(4, 4), blk, 0, stream>>>(Wi2, wi2T, 128, 128);
  k_transpose_convert<<<dim3(16, 16), blk, 0, stream>>>(Wt1, wt1T, 512, 512);
  k_transpose_convert<<<dim3(16, 16), blk, 0, stream>>>(Wt2, wt2T, 512, 512);
  k_transpose_convert<<<dim3(3, 2048), blk, 0, stream>>>(Wh, whT, 65536, 96);

  // ---- InterPatchMixing: transpose, 2 gemms, transpose back
  k_transpose_b16<<<dim3(16, 4, 64), blk, 0, stream>>>(o1b, bufB, 128, 512);
  k_gemm<1><<<dim3(256, 1), blk, 0, stream>>>(bufB, wi1T, bi1, o1b, 32768, 128, 128);
  k_gemm<0><<<dim3(256, 1), blk, 0, stream>>>(o1b, wi2T, bi2, bufB, 32768, 128, 128);
  k_transpose_b16<<<dim3(4, 16, 64), blk, 0, stream>>>(bufB, o1b, 512, 128);

  // ---- IntraPatchMixing
  k_gemm<1><<<dim3(64, 4), blk, 0, stream>>>(o1b, wt1T, bt1, bufB, 8192, 512, 512);
  k_gemm<0><<<dim3(64, 4), blk, 0, stream>>>(bufB, wt2T, bt2, o1b, 8192, 512, 512);

  // ---- Flatten head
  k_head_partial<<<128, blk, 0, stream>>>(o1b, whT, hp);
  k_head_reduce<<<24, blk, 0, stream>>>(hp, bh, out);
}